// Round 6
// baseline (193.781 us; speedup 1.0000x reference)
//
#include <hip/hip_runtime.h>

// B=8, L=512, K=512, D=M=N=P=64, all fp32.
// ws: vkc = 8*512*64 floats (1 MB).

// ---------------------------------------------------------------------------
// K1 (proven, ~6.2 TB/s): vkc[b,k,n] = sum_p vk[b,k,p,n] * vexp[b,k,p]
// ---------------------------------------------------------------------------
__global__ __launch_bounds__(256) void vkc_kernel(const float* __restrict__ vk,
                                                  const float* __restrict__ vexp,
                                                  float* __restrict__ vkc) {
    const int wave = (blockIdx.x << 2) + (threadIdx.x >> 6);  // b*512 + k
    const int lane = threadIdx.x & 63;

    const float ve_reg = vexp[wave * 64 + lane];
    const int n0 = (lane & 15) << 2;
    const float* base = vk + (long)wave * 4096;

    float ax = 0.f, ay = 0.f, az = 0.f, aw = 0.f;
    #pragma unroll
    for (int it = 0; it < 16; ++it) {
        const int p = (lane >> 4) + (it << 2);
        const float4 v4 = *(const float4*)(base + p * 64 + n0);
        const float w = __shfl(ve_reg, p, 64);
        ax += v4.x * w; ay += v4.y * w; az += v4.z * w; aw += v4.w * w;
    }
    ax += __shfl_down(ax, 32, 64); ax += __shfl_down(ax, 16, 64);
    ay += __shfl_down(ay, 32, 64); ay += __shfl_down(ay, 16, 64);
    az += __shfl_down(az, 32, 64); az += __shfl_down(az, 16, 64);
    aw += __shfl_down(aw, 32, 64); aw += __shfl_down(aw, 16, 64);

    if ((lane & 48) == 0) {
        float4 r; r.x = ax; r.y = ay; r.z = az; r.w = aw;
        *(float4*)(vkc + wave * 64 + n0) = r;
    }
}

// LDS-only barrier: drain LDS (lgkmcnt) but keep global loads (vmcnt) in
// flight across the barrier. All inter-phase deps below are LDS-only.
__device__ __forceinline__ void lds_barrier() {
    asm volatile("s_waitcnt lgkmcnt(0)" ::: "memory");
    __builtin_amdgcn_s_barrier();
}

// ---------------------------------------------------------------------------
// Fused: per (batch, 4 l-rows), 512 threads, 1024 blocks.
// P1 REWRITTEN: coalesced scores. Wave wv owns k-rows wv*64..+63; per
// wave-load, 4 groups of 16 lanes read 4 CONSECUTIVE k-rows (1 KB contiguous
// -- the K1 pattern), each group dot-reduces its row via width-16 shfl.
// This replaces the old thread-owns-row layout whose 256B-stride gather
// (64 cache lines / instr) was the measured ~20 us lump (rounds 0-5).
//   P1 scores -> P2 softmax -> P3 tmp partials (+ vq prefetch) -> P4 reduce
//   -> P5 vq.tmp partial dots -> P6 residual + LN -> out
// ---------------------------------------------------------------------------
__global__ __launch_bounds__(512) void score_out_kernel(
        const float* __restrict__ q,
        const float* __restrict__ k,
        const float* __restrict__ vkc,
        const float* __restrict__ scale_p,
        const float* __restrict__ vq,
        const float* __restrict__ gamma,
        const float* __restrict__ beta,
        float* __restrict__ out) {
    __shared__ float sc[4][512];          // 8 KB
    __shared__ float tp[8][4][64];        // 8 KB
    __shared__ float tmp_s[4][64];        // 1 KB
    __shared__ float attn_s[4][64];       // 1 KB

    const int t = threadIdx.x;
    const int wv = t >> 6;
    const int lane = t & 63;
    const int batch = blockIdx.x >> 7;
    const int l0 = (blockIdx.x & 127) << 2;

    const float scale = scale_p[0];
    const int ksub = lane >> 4;
    const int n0 = (lane & 15) << 2;

    // residual operand for P6 (waves 0-3 use it); L2-hot
    const float qres = q[(batch * 512 + l0 + (wv & 3)) * 64 + lane];

    // ---- P1: coalesced scores. Wave wv -> k-rows [wv*64, wv*64+64) ----
    {
        // per-lane q fragments: lane covers d-range n0..n0+3 for each l row
        float4 ql[4];
        #pragma unroll
        for (int l = 0; l < 4; ++l)
            ql[l] = *(const float4*)(q + (batch * 512 + l0 + l) * 64 + n0);

        const int kbeg = wv << 6;
        const float* kb = k + (long)(batch * 512 + kbeg) * 64;
        #pragma unroll
        for (int i = 0; i < 16; ++i) {
            const int r = (i << 2) + ksub;                    // row in [0,64)
            const float4 k4 = *(const float4*)(kb + r * 64 + n0);  // 1 KB/instr
            #pragma unroll
            for (int l = 0; l < 4; ++l) {
                float p = k4.x * ql[l].x + k4.y * ql[l].y
                        + k4.z * ql[l].z + k4.w * ql[l].w;
                p += __shfl_down(p, 8, 16);
                p += __shfl_down(p, 4, 16);
                p += __shfl_down(p, 2, 16);
                p += __shfl_down(p, 1, 16);
                if ((lane & 15) == 0) sc[l][kbeg + r] = scale * p;
            }
        }
    }
    lds_barrier();

    // ---- P2: softmax over K=512; wave wv (<4) -> row wv ----
    if (wv < 4) {
        float vv[8]; float mx = -1e30f;
        #pragma unroll
        for (int j = 0; j < 8; ++j) { vv[j] = sc[wv][lane + 64 * j]; mx = fmaxf(mx, vv[j]); }
        #pragma unroll
        for (int off = 32; off; off >>= 1) mx = fmaxf(mx, __shfl_xor(mx, off, 64));
        float s = 0.f;
        #pragma unroll
        for (int j = 0; j < 8; ++j) { vv[j] = __expf(vv[j] - mx); s += vv[j]; }
        #pragma unroll
        for (int off = 32; off; off >>= 1) s += __shfl_xor(s, off, 64);
        const float inv = 1.0f / s;
        #pragma unroll
        for (int j = 0; j < 8; ++j) sc[wv][lane + 64 * j] = vv[j] * inv;
    }
    lds_barrier();

    // ---- P3: tmp partials over this wave's 64 k; vq prefetch interleaved ---
    const int row = batch * 512 + l0 + (wv & 3);    // this wave's output row
    const int half = wv >> 2;                       // which half of the M dots
    const float* vql = vq + (long)row * 4096 + half * 2048;
    float4 v[8];                                    // P5 operand (issue-early)
    {
        const float* vkcb = vkc + batch * 512 * 64;
        const int kbeg = wv << 6;
        float4 a[4];
        #pragma unroll
        for (int l = 0; l < 4; ++l) { a[l].x = 0.f; a[l].y = 0.f; a[l].z = 0.f; a[l].w = 0.f; }
        #pragma unroll
        for (int i = 0; i < 16; ++i) {
            if (i < 8) v[i] = *(const float4*)(vql + i * 256 + lane * 4);  // T14
            const int kk = kbeg + (i << 2) + ksub;
            const float4 v4 = *(const float4*)(vkcb + kk * 64 + n0);  // 1 KB/instr
            #pragma unroll
            for (int l = 0; l < 4; ++l) {
                const float w = sc[l][kk];
                a[l].x += w * v4.x; a[l].y += w * v4.y;
                a[l].z += w * v4.z; a[l].w += w * v4.w;
            }
        }
        #pragma unroll
        for (int l = 0; l < 4; ++l) {
            a[l].x += __shfl_down(a[l].x, 32, 64); a[l].x += __shfl_down(a[l].x, 16, 64);
            a[l].y += __shfl_down(a[l].y, 32, 64); a[l].y += __shfl_down(a[l].y, 16, 64);
            a[l].z += __shfl_down(a[l].z, 32, 64); a[l].z += __shfl_down(a[l].z, 16, 64);
            a[l].w += __shfl_down(a[l].w, 32, 64); a[l].w += __shfl_down(a[l].w, 16, 64);
        }
        if (lane < 16) {
            #pragma unroll
            for (int l = 0; l < 4; ++l)
                *(float4*)&tp[wv][l][lane << 2] = a[l];
        }
    }
    lds_barrier();

    // ---- P4: reduce 8 wave partials into tmp_s ----
    if (t < 256) {
        const int l = t >> 6, n = t & 63;
        float s = tp[0][l][n];
        #pragma unroll
        for (int w = 1; w < 8; ++w) s += tp[w][l][n];
        tmp_s[l][n] = s;
    }
    lds_barrier();

    // ---- P5: wave wv -> row l0+(wv&3), M-half (wv>>2): 32 of 64 dots ----
    {
        const float4 t4 = *(const float4*)&tmp_s[wv & 3][n0];

        #pragma unroll
        for (int j = 0; j < 8; ++j) {
            float part = v[j].x * t4.x + v[j].y * t4.y + v[j].z * t4.z + v[j].w * t4.w;
            part += __shfl_down(part, 8, 16);
            part += __shfl_down(part, 4, 16);
            part += __shfl_down(part, 2, 16);
            part += __shfl_down(part, 1, 16);
            if ((lane & 15) == 0)
                attn_s[wv & 3][half * 32 + j * 4 + (lane >> 4)] = part;
        }
    }
    lds_barrier();

    // ---- P6: waves 0-3: row l0+wv: residual + LN -> out ----
    if (t < 256) {
        const int orow = batch * 512 + l0 + wv;
        const float x = qres + attn_s[wv][lane];
        float s1 = x, s2 = x * x;
        #pragma unroll
        for (int off = 32; off; off >>= 1) {
            s1 += __shfl_xor(s1, off, 64);
            s2 += __shfl_xor(s2, off, 64);
        }
        const float mean = s1 * (1.0f / 64.0f);
        const float var = s2 * (1.0f / 64.0f) - mean * mean;
        const float r = rsqrtf(var + 1e-3f);
        out[orow * 64 + lane] = (x - mean) * r * gamma[lane] + beta[lane];
    }
}

extern "C" void kernel_launch(void* const* d_in, const int* in_sizes, int n_in,
                              void* d_out, int out_size, void* d_ws, size_t ws_size,
                              hipStream_t stream) {
    const float* q     = (const float*)d_in[0];
    const float* k     = (const float*)d_in[1];
    const float* vq    = (const float*)d_in[2];
    const float* vk    = (const float*)d_in[3];
    const float* vexp  = (const float*)d_in[4];
    const float* scale = (const float*)d_in[5];
    const float* gamma = (const float*)d_in[6];
    const float* beta  = (const float*)d_in[7];
    float* out = (float*)d_out;

    float* vkc = (float*)d_ws;                 // 1 MB

    vkc_kernel<<<1024, 256, 0, stream>>>(vk, vexp, vkc);
    score_out_kernel<<<1024, 512, 0, stream>>>(q, k, vkc, scale, vq, gamma, beta, out);
}

// Round 7
// 173.982 us; speedup vs baseline: 1.1138x; 1.1138x over previous
//
#include <hip/hip_runtime.h>

// B=8, L=512, K=512, D=M=N=P=64, all fp32.
// ws: vkc = 1 MB | kT = 1 MB  (k transposed per batch: kT[b][d][k])

// ---------------------------------------------------------------------------
// K0: kT[b][d][kk] = k[b][kk][d].  64 blocks x 256 thr, LDS 64x65 tile.
// ---------------------------------------------------------------------------
__global__ __launch_bounds__(256) void kt_kernel(const float* __restrict__ k,
                                                 float* __restrict__ kT) {
    __shared__ float tile[64][65];
    const int b  = blockIdx.x >> 3;
    const int k0 = (blockIdx.x & 7) << 6;
    const int t  = threadIdx.x;
    const int r  = t >> 2;                 // 0..63
    const int c0 = (t & 3) << 4;           // 0,16,32,48

    const float* src = k + ((long)(b * 512 + k0 + r)) * 64 + c0;
    #pragma unroll
    for (int m = 0; m < 4; ++m) {
        const float4 v = *(const float4*)(src + 4 * m);
        tile[r][c0 + 4 * m + 0] = v.x;
        tile[r][c0 + 4 * m + 1] = v.y;
        tile[r][c0 + 4 * m + 2] = v.z;
        tile[r][c0 + 4 * m + 3] = v.w;
    }
    __syncthreads();
    float* dst = kT + ((long)b * 64 + r) * 512 + k0 + c0;
    #pragma unroll
    for (int m = 0; m < 4; ++m) {
        float4 v;
        v.x = tile[c0 + 4 * m + 0][r];
        v.y = tile[c0 + 4 * m + 1][r];
        v.z = tile[c0 + 4 * m + 2][r];
        v.w = tile[c0 + 4 * m + 3][r];
        *(float4*)(dst + 4 * m) = v;
    }
}

// ---------------------------------------------------------------------------
// K1 (proven, ~6.2 TB/s): vkc[b,k,n] = sum_p vk[b,k,p,n] * vexp[b,k,p]
// ---------------------------------------------------------------------------
__global__ __launch_bounds__(256) void vkc_kernel(const float* __restrict__ vk,
                                                  const float* __restrict__ vexp,
                                                  float* __restrict__ vkc) {
    const int wave = (blockIdx.x << 2) + (threadIdx.x >> 6);  // b*512 + k
    const int lane = threadIdx.x & 63;

    const float ve_reg = vexp[wave * 64 + lane];
    const int n0 = (lane & 15) << 2;
    const float* base = vk + (long)wave * 4096;

    float ax = 0.f, ay = 0.f, az = 0.f, aw = 0.f;
    #pragma unroll
    for (int it = 0; it < 16; ++it) {
        const int p = (lane >> 4) + (it << 2);
        const float4 v4 = *(const float4*)(base + p * 64 + n0);
        const float w = __shfl(ve_reg, p, 64);
        ax += v4.x * w; ay += v4.y * w; az += v4.z * w; aw += v4.w * w;
    }
    ax += __shfl_down(ax, 32, 64); ax += __shfl_down(ax, 16, 64);
    ay += __shfl_down(ay, 32, 64); ay += __shfl_down(ay, 16, 64);
    az += __shfl_down(az, 32, 64); az += __shfl_down(az, 16, 64);
    aw += __shfl_down(aw, 32, 64); aw += __shfl_down(aw, 16, 64);

    if ((lane & 48) == 0) {
        float4 r; r.x = ax; r.y = ay; r.z = az; r.w = aw;
        *(float4*)(vkc + wave * 64 + n0) = r;
    }
}

// LDS-only barrier: drain LDS (lgkmcnt) but keep global loads (vmcnt) in
// flight across the barrier. All inter-phase deps below are LDS-only.
__device__ __forceinline__ void lds_barrier() {
    asm volatile("s_waitcnt lgkmcnt(0)" ::: "memory");
    __builtin_amdgcn_s_barrier();
}

// ---------------------------------------------------------------------------
// Fused: per (batch, 4 l-rows), 512 threads, 1024 blocks.
// P1 via kT: thread t owns k-row t; reads kT[dc][t] -> lane-consecutive
// COALESCED loads, zero shuffles, zero LDS staging. q stays on the scalar
// pipe (block-uniform s_load_dwordx4). Replaces both the R4 gather
// (64 cache lines/instr) and the R6 shfl-reduce (256 DS-ops/wave).
//   P1 scores -> P2 softmax -> P3 tmp partials (+ vq prefetch) -> P4 reduce
//   -> P5 vq.tmp partial dots -> P6 residual + LN -> out   (P2-P6 = R4)
// ---------------------------------------------------------------------------
__global__ __launch_bounds__(512) void score_out_kernel(
        const float* __restrict__ q,
        const float* __restrict__ kT,
        const float* __restrict__ vkc,
        const float* __restrict__ scale_p,
        const float* __restrict__ vq,
        const float* __restrict__ gamma,
        const float* __restrict__ beta,
        float* __restrict__ out) {
    __shared__ float sc[4][512];          // 8 KB
    __shared__ float tp[8][4][64];        // 8 KB
    __shared__ float tmp_s[4][64];        // 1 KB
    __shared__ float attn_s[4][64];       // 1 KB

    const int t = threadIdx.x;
    const int wv = t >> 6;
    const int lane = t & 63;
    const int batch = blockIdx.x >> 7;
    const int l0 = (blockIdx.x & 127) << 2;

    const float scale = scale_p[0];
    const int ksub = lane >> 4;
    const int n0 = (lane & 15) << 2;

    // residual operand for P6 (waves 0-3 use it); L2-hot
    const float qres = q[(batch * 512 + l0 + (wv & 3)) * 64 + lane];

    const float* qbase = q + (batch * 512 + l0) * 64;   // block-uniform

    // ---- P1: scores via kT. thread t owns k-row t; coalesced kT reads ----
    {
        const float* ktb = kT + (long)batch * 64 * 512 + t;
        float acc0 = 0.f, acc1 = 0.f, acc2 = 0.f, acc3 = 0.f;
        #pragma unroll
        for (int dc4 = 0; dc4 < 16; ++dc4) {
            const float4 qv0 = ((const float4*)(qbase +   0))[dc4];  // s_load
            const float4 qv1 = ((const float4*)(qbase +  64))[dc4];
            const float4 qv2 = ((const float4*)(qbase + 128))[dc4];
            const float4 qv3 = ((const float4*)(qbase + 192))[dc4];
            const float k0v = ktb[(dc4 * 4 + 0) * 512];   // 256 B/wave, coalesced
            const float k1v = ktb[(dc4 * 4 + 1) * 512];
            const float k2v = ktb[(dc4 * 4 + 2) * 512];
            const float k3v = ktb[(dc4 * 4 + 3) * 512];
            acc0 += qv0.x * k0v + qv0.y * k1v + qv0.z * k2v + qv0.w * k3v;
            acc1 += qv1.x * k0v + qv1.y * k1v + qv1.z * k2v + qv1.w * k3v;
            acc2 += qv2.x * k0v + qv2.y * k1v + qv2.z * k2v + qv2.w * k3v;
            acc3 += qv3.x * k0v + qv3.y * k1v + qv3.z * k2v + qv3.w * k3v;
        }
        sc[0][t] = scale * acc0;
        sc[1][t] = scale * acc1;
        sc[2][t] = scale * acc2;
        sc[3][t] = scale * acc3;
    }
    lds_barrier();

    // ---- P2: softmax over K=512; wave wv (<4) -> row wv ----
    if (wv < 4) {
        float vv[8]; float mx = -1e30f;
        #pragma unroll
        for (int j = 0; j < 8; ++j) { vv[j] = sc[wv][lane + 64 * j]; mx = fmaxf(mx, vv[j]); }
        #pragma unroll
        for (int off = 32; off; off >>= 1) mx = fmaxf(mx, __shfl_xor(mx, off, 64));
        float s = 0.f;
        #pragma unroll
        for (int j = 0; j < 8; ++j) { vv[j] = __expf(vv[j] - mx); s += vv[j]; }
        #pragma unroll
        for (int off = 32; off; off >>= 1) s += __shfl_xor(s, off, 64);
        const float inv = 1.0f / s;
        #pragma unroll
        for (int j = 0; j < 8; ++j) sc[wv][lane + 64 * j] = vv[j] * inv;
    }
    lds_barrier();

    // ---- P3: tmp partials over this wave's 64 k; vq prefetch interleaved ---
    const int row = batch * 512 + l0 + (wv & 3);    // this wave's output row
    const int half = wv >> 2;                       // which half of the M dots
    const float* vql = vq + (long)row * 4096 + half * 2048;
    float4 v[8];                                    // P5 operand (issue-early)
    {
        const float* vkcb = vkc + batch * 512 * 64;
        const int kbeg = wv << 6;
        float4 a[4];
        #pragma unroll
        for (int l = 0; l < 4; ++l) { a[l].x = 0.f; a[l].y = 0.f; a[l].z = 0.f; a[l].w = 0.f; }
        #pragma unroll
        for (int i = 0; i < 16; ++i) {
            if (i < 8) v[i] = *(const float4*)(vql + i * 256 + lane * 4);  // T14
            const int kk = kbeg + (i << 2) + ksub;
            const float4 v4 = *(const float4*)(vkcb + kk * 64 + n0);  // 1 KB/instr
            #pragma unroll
            for (int l = 0; l < 4; ++l) {
                const float w = sc[l][kk];
                a[l].x += w * v4.x; a[l].y += w * v4.y;
                a[l].z += w * v4.z; a[l].w += w * v4.w;
            }
        }
        #pragma unroll
        for (int l = 0; l < 4; ++l) {
            a[l].x += __shfl_down(a[l].x, 32, 64); a[l].x += __shfl_down(a[l].x, 16, 64);
            a[l].y += __shfl_down(a[l].y, 32, 64); a[l].y += __shfl_down(a[l].y, 16, 64);
            a[l].z += __shfl_down(a[l].z, 32, 64); a[l].z += __shfl_down(a[l].z, 16, 64);
            a[l].w += __shfl_down(a[l].w, 32, 64); a[l].w += __shfl_down(a[l].w, 16, 64);
        }
        if (lane < 16) {
            #pragma unroll
            for (int l = 0; l < 4; ++l)
                *(float4*)&tp[wv][l][lane << 2] = a[l];
        }
    }
    lds_barrier();

    // ---- P4: reduce 8 wave partials into tmp_s ----
    if (t < 256) {
        const int l = t >> 6, n = t & 63;
        float s = tp[0][l][n];
        #pragma unroll
        for (int w = 1; w < 8; ++w) s += tp[w][l][n];
        tmp_s[l][n] = s;
    }
    lds_barrier();

    // ---- P5: wave wv -> row l0+(wv&3), M-half (wv>>2): 32 of 64 dots ----
    {
        const float4 t4 = *(const float4*)&tmp_s[wv & 3][n0];

        #pragma unroll
        for (int j = 0; j < 8; ++j) {
            float part = v[j].x * t4.x + v[j].y * t4.y + v[j].z * t4.z + v[j].w * t4.w;
            part += __shfl_down(part, 8, 16);
            part += __shfl_down(part, 4, 16);
            part += __shfl_down(part, 2, 16);
            part += __shfl_down(part, 1, 16);
            if ((lane & 15) == 0)
                attn_s[wv & 3][half * 32 + j * 4 + (lane >> 4)] = part;
        }
    }
    lds_barrier();

    // ---- P6: waves 0-3: row l0+wv: residual + LN -> out ----
    if (t < 256) {
        const int orow = batch * 512 + l0 + wv;
        const float x = qres + attn_s[wv][lane];
        float s1 = x, s2 = x * x;
        #pragma unroll
        for (int off = 32; off; off >>= 1) {
            s1 += __shfl_xor(s1, off, 64);
            s2 += __shfl_xor(s2, off, 64);
        }
        const float mean = s1 * (1.0f / 64.0f);
        const float var = s2 * (1.0f / 64.0f) - mean * mean;
        const float r = rsqrtf(var + 1e-3f);
        out[orow * 64 + lane] = (x - mean) * r * gamma[lane] + beta[lane];
    }
}

extern "C" void kernel_launch(void* const* d_in, const int* in_sizes, int n_in,
                              void* d_out, int out_size, void* d_ws, size_t ws_size,
                              hipStream_t stream) {
    const float* q     = (const float*)d_in[0];
    const float* k     = (const float*)d_in[1];
    const float* vq    = (const float*)d_in[2];
    const float* vk    = (const float*)d_in[3];
    const float* vexp  = (const float*)d_in[4];
    const float* scale = (const float*)d_in[5];
    const float* gamma = (const float*)d_in[6];
    const float* beta  = (const float*)d_in[7];
    float* out = (float*)d_out;

    float* vkc = (float*)d_ws;                 // 1 MB
    float* kT  = vkc + 8 * 512 * 64;           // 1 MB

    kt_kernel<<<64, 256, 0, stream>>>(k, kT);
    vkc_kernel<<<1024, 256, 0, stream>>>(vk, vexp, vkc);
    score_out_kernel<<<1024, 512, 0, stream>>>(q, kT, vkc, scale, vq, gamma, beta, out);
}